// Round 1
// baseline (259.609 us; speedup 1.0000x reference)
//
#include <hip/hip_runtime.h>

// Decay-based linear recurrent scan:  S_t = d*S_{t-1} + (1-d)*kv_t ; out_t = q_t*S_t
// fp32, (T,B,H,V,D) = (128,16,8,25,64). 204800 independent channels.
//
// Round-3 design: chunked (blocked) scan to fix the latency-bound regime.
//   v4 had 800 waves total (3.1/CU, 7% occupancy) and the compiler collapsed its
//   register double-buffer (VGPR_Count=44 < the 64+ the buffers need) -> ~2KB MLP
//   per wave -> 2.0 TB/s. The recurrence is linear, so split T=128 into 8 chunks
//   of 16: pass 1 emits per-chunk contributions B_c, pass 2 folds chunk prefixes
//   (A = d^16 via 4 squarings) and emits outputs. 6400 waves/pass = 25 waves/CU.
//   kv is read in both passes but stays LLC-resident (105 MB << 256 MB); q loads
//   and out stores are non-temporal to avoid evicting it.

#define T_DIM 128
#define CH    204800            // B*H*V*D
#define CH4   (CH / 4)          // 51200 float4 channels
#define VD    (25 * 64)         // V*D
#define L_CHUNK 16
#define N_CHUNK (T_DIM / L_CHUNK)        // 8
#define BLK 256
#define BLOCKS_PER_CHUNK (CH4 / BLK)     // 200

typedef float f32x4 __attribute__((ext_vector_type(4)));

static __device__ __forceinline__ f32x4 scan_step(f32x4 d, f32x4 omd, f32x4 S, f32x4 k) {
    f32x4 r;
    r[0] = fmaf(d[0], S[0], omd[0] * k[0]);
    r[1] = fmaf(d[1], S[1], omd[1] * k[1]);
    r[2] = fmaf(d[2], S[2], omd[2] * k[2]);
    r[3] = fmaf(d[3], S[3], omd[3] * k[3]);
    return r;
}

// ---------------------------------------------------------------- pass 1 ----
// Per (float4-channel i, chunk c): B_c = local scan of kv over 16 steps from 0.
__global__ __launch_bounds__(BLK) void sss_pass1(
    const f32x4* __restrict__ kv,
    const float* __restrict__ decay,
    f32x4* __restrict__ ws)
{
    const int b = blockIdx.x;
    const int c = b / BLOCKS_PER_CHUNK;                       // chunk (block-uniform)
    const int i = (b % BLOCKS_PER_CHUNK) * BLK + threadIdx.x; // float4 channel
    const int e0 = i * 4;
    const int dd = e0 & 63;          // d-offset within D=64
    const int h  = (e0 / VD) & 7;    // head

    const f32x4 d = *(const f32x4*)(decay + h * 64 + dd);
    const f32x4 omd = 1.0f - d;

    const f32x4* __restrict__ kp = kv + (size_t)c * L_CHUNK * CH4 + i;

    f32x4 B = (f32x4)0.0f;
    #pragma unroll
    for (int j = 0; j < L_CHUNK; ++j) {
        f32x4 k = kp[(size_t)j * CH4];
        B = scan_step(d, omd, B, k);
    }
    ws[(size_t)c * CH4 + i] = B;
}

// ---------------------------------------------------------------- pass 2 ----
// Per (float4-channel i, chunk c): S_in = sum_{c'<c} A^(c-1-c') B_c' (A = d^16),
// then scan the chunk's 16 steps and write out_t = q_t * S_t.
__global__ __launch_bounds__(BLK) void sss_pass2(
    const f32x4* __restrict__ q,
    const f32x4* __restrict__ kv,
    const float* __restrict__ decay,
    const f32x4* __restrict__ ws,
    f32x4* __restrict__ out)
{
    const int b = blockIdx.x;
    const int c = b / BLOCKS_PER_CHUNK;                       // chunk (block-uniform)
    const int i = (b % BLOCKS_PER_CHUNK) * BLK + threadIdx.x;
    const int e0 = i * 4;
    const int dd = e0 & 63;
    const int h  = (e0 / VD) & 7;

    const f32x4 d = *(const f32x4*)(decay + h * 64 + dd);
    const f32x4 omd = 1.0f - d;

    // A = d^16 via 4 squarings
    f32x4 A = d;
    A = A * A;   // d^2
    A = A * A;   // d^4
    A = A * A;   // d^8
    A = A * A;   // d^16

    // fold chunk prefixes (block-uniform trip count -> no divergence;
    // reads are coalesced and L2/LLC-resident: 6.5 MB working set)
    f32x4 S = (f32x4)0.0f;
    for (int cp = 0; cp < c; ++cp) {
        f32x4 B = ws[(size_t)cp * CH4 + i];
        S[0] = fmaf(A[0], S[0], B[0]);
        S[1] = fmaf(A[1], S[1], B[1]);
        S[2] = fmaf(A[2], S[2], B[2]);
        S[3] = fmaf(A[3], S[3], B[3]);
    }

    const size_t base = (size_t)c * L_CHUNK * CH4 + i;
    const f32x4* __restrict__ kp = kv + base;
    const f32x4* __restrict__ qp = q + base;
    f32x4* __restrict__ op = out + base;

    #pragma unroll
    for (int j = 0; j < L_CHUNK; ++j) {
        f32x4 k  = kp[(size_t)j * CH4];
        f32x4 qq = __builtin_nontemporal_load(qp + (size_t)j * CH4);  // q: no reuse
        S = scan_step(d, omd, S, k);
        f32x4 o = qq * S;
        __builtin_nontemporal_store(o, op + (size_t)j * CH4);         // out: no reuse
    }
}

// ------------------------------------------------- fallback (round-2 kernel) ----
// Used only if the harness workspace is too small for the chunk summaries.
__global__ __launch_bounds__(64) void sss_scan_v4(
    const f32x4* __restrict__ q,
    const f32x4* __restrict__ kv,
    const float* __restrict__ decay,
    f32x4* __restrict__ out)
{
    const int i  = blockIdx.x * 64 + threadIdx.x;
    const int e0 = i * 4;
    const int dd = e0 & 63;
    const int h  = (e0 / VD) & 7;

    const f32x4 d = *(const f32x4*)(decay + h * 64 + dd);
    const f32x4 omd = 1.0f - d;

    const f32x4* __restrict__ qp = q  + i;
    const f32x4* __restrict__ kp = kv + i;
    f32x4*       __restrict__ op = out + i;

    f32x4 S = (f32x4)0.0f;
    for (int t = 0; t < T_DIM; ++t) {
        f32x4 k  = kp[(size_t)t * CH4];
        f32x4 qq = qp[(size_t)t * CH4];
        S = scan_step(d, omd, S, k);
        op[(size_t)t * CH4] = qq * S;
    }
}

extern "C" void kernel_launch(void* const* d_in, const int* in_sizes, int n_in,
                              void* d_out, int out_size, void* d_ws, size_t ws_size,
                              hipStream_t stream) {
    const f32x4* q     = (const f32x4*)d_in[0];
    const f32x4* kv    = (const f32x4*)d_in[1];
    const float* decay = (const float*)d_in[2];
    f32x4* out = (f32x4*)d_out;

    const size_t ws_need = (size_t)N_CHUNK * CH4 * sizeof(f32x4);   // 6.55 MB
    if (d_ws != nullptr && ws_size >= ws_need) {
        f32x4* ws = (f32x4*)d_ws;
        sss_pass1<<<N_CHUNK * BLOCKS_PER_CHUNK, BLK, 0, stream>>>(kv, decay, ws);
        sss_pass2<<<N_CHUNK * BLOCKS_PER_CHUNK, BLK, 0, stream>>>(q, kv, decay, ws, out);
    } else {
        sss_scan_v4<<<CH4 / 64, 64, 0, stream>>>(q, kv, decay, out);
    }
}